// Round 1
// baseline (2324.238 us; speedup 1.0000x reference)
//
#include <hip/hip_runtime.h>
#include <hip/hip_bf16.h>

// ---------------------------------------------------------------------------
// Fused 4-branch conv block + BN + top-k channel select (MI355X / gfx950)
// Round 1: correctness-first fused fp32-accumulate kernel, bf16 LDS staging.
// ---------------------------------------------------------------------------

#define NB 8
#define NC 64
#define MID 32
#define NH 256
#define NW 256
#define TILE 16
#define HALO 18          // TILE + 2
#define NPOS (HALO*HALO) // 324

// ws float-array layout (after 128 ints for och)
constexpr int OFF_SSC = 0;               // 128  sigmoid(c_score)
constexpr int OFF_WM  = 128;             // 18432 main 3x3 folded  [c][tap][o]
constexpr int OFF_BM  = OFF_WM + 18432;  // 32
constexpr int OFF_W11 = OFF_BM + 32;     // 2048  1x1 folded [c][o]
constexpr int OFF_B11 = OFF_W11 + 2048;  // 32
constexpr int OFF_W31 = OFF_B11 + 32;    // 2048  3x3-branch 1x1 folded [c][o]
constexpr int OFF_B31 = OFF_W31 + 2048;  // 32
constexpr int OFF_W32 = OFF_B31 + 32;    // 9216  3x3-branch 3x3 folded [c][tap][o]
constexpr int OFF_B32 = OFF_W32 + 9216;  // 32
constexpr int OFF_WAV = OFF_B32 + 32;    // 2048  avg-branch 1x1 folded [c][o]
constexpr int OFF_BAV = OFF_WAV + 2048;  // 32
constexpr int OFF_S2  = OFF_BAV + 32;    // 32   bn_avg_2 scale
constexpr int OFF_T2B = OFF_S2 + 32;     // 32   bn_avg_2 bias
constexpr int WSF_TOTAL = OFF_T2B + 32;  // 34144 floats

__device__ __forceinline__ float bn_inv(const float* bn, int o) {
    return bn[o] * rsqrtf(bn[96 + o] + 1e-5f);
}
__device__ __forceinline__ float bn_bias(const float* bn, int o) {
    float inv = bn_inv(bn, o);
    return bn[32 + o] - bn[64 + o] * inv;
}

// ---------------------------------------------------------------------------
// prep: top-k ranks + BN-folded weights into ws
// ---------------------------------------------------------------------------
__global__ void prep_kernel(
    const float* __restrict__ c_score,
    const float* __restrict__ w_main, const float* __restrict__ bn_main,
    const float* __restrict__ w_1x1,  const float* __restrict__ bn_1x1,
    const float* __restrict__ w_3x3_1,const float* __restrict__ bn_3x3_1,
    const float* __restrict__ w_3x3_2,const float* __restrict__ bn_3x3_2,
    const float* __restrict__ w_avg,  const float* __restrict__ bn_avg_1,
    const float* __restrict__ bn_avg_2,
    int* __restrict__ och, float* __restrict__ wsf)
{
    const int t = threadIdx.x;

    if (t < 128) {
        // stable rank (ties -> lower index wins), matches lax.top_k
        float sj = c_score[t];
        int r = 0;
        for (int i = 0; i < 128; i++) {
            float si = c_score[i];
            r += (si > sj) || (si == sj && i < t);
        }
        och[t] = (r < 64) ? r : -1;
        wsf[OFF_SSC + t] = 1.f / (1.f + expf(-sj));
    }

    // main 3x3: [o][c][3][3] -> [c][tap][o], scaled by BN inv
    for (int i = t; i < 18432; i += 256) {
        int o = i & 31, tap = (i >> 5) % 9, c = i / 288;
        wsf[OFF_WM + i] = w_main[o * 576 + c * 9 + tap] * bn_inv(bn_main, o);
    }
    // the three 1x1 convs: [o][c] -> [c][o]
    for (int i = t; i < 2048; i += 256) {
        int o = i & 31, c = i >> 5;
        wsf[OFF_W11 + i] = w_1x1[o * 64 + c]   * bn_inv(bn_1x1, o);
        wsf[OFF_W31 + i] = w_3x3_1[o * 64 + c] * bn_inv(bn_3x3_1, o);
        wsf[OFF_WAV + i] = w_avg[o * 64 + c]   * bn_inv(bn_avg_1, o);
    }
    // 3x3 branch second conv: [o][c][3][3] -> [c][tap][o]
    for (int i = t; i < 9216; i += 256) {
        int o = i & 31, tap = (i >> 5) % 9, c = i / 288;
        wsf[OFF_W32 + i] = w_3x3_2[o * 288 + c * 9 + tap] * bn_inv(bn_3x3_2, o);
    }
    if (t < 32) {
        wsf[OFF_BM  + t] = bn_bias(bn_main,  t);
        wsf[OFF_B11 + t] = bn_bias(bn_1x1,   t);
        wsf[OFF_B31 + t] = bn_bias(bn_3x3_1, t);
        wsf[OFF_B32 + t] = bn_bias(bn_3x3_2, t);
        wsf[OFF_BAV + t] = bn_bias(bn_avg_1, t);
        float inv2 = bn_inv(bn_avg_2, t);
        wsf[OFF_S2  + t] = inv2;
        wsf[OFF_T2B + t] = bn_avg_2[32 + t] - bn_avg_2[64 + t] * inv2;
    }
}

// ---------------------------------------------------------------------------
// fused main kernel: one 16x16 spatial tile per block, all 4 branches,
// scatter selected channels straight to d_out.
// ---------------------------------------------------------------------------
__global__ __launch_bounds__(256, 1) void fused_kernel(
    const float* __restrict__ x, const float* __restrict__ wsf,
    const int* __restrict__ och_g, float* __restrict__ out)
{
    __shared__ __hip_bfloat16 xs[NC][NPOS];    // 41472 B  x halo tile
    __shared__ __hip_bfloat16 t1s[MID][NPOS];  // 20736 B  bn(conv1x1 w_3x3_1)
    __shared__ __hip_bfloat16 t2s[MID][NPOS];  // 20736 B  bn(conv1x1 w_avg)
    __shared__ __align__(16) float wb[4608];   // 18432 B  staged weights
    __shared__ int och[128];
    __shared__ float ssc[128];

    const int t = threadIdx.x;
    const int b = blockIdx.z;
    const int x0 = blockIdx.x * TILE, y0 = blockIdx.y * TILE;

    if (t < 128) { och[t] = och_g[t]; ssc[t] = wsf[OFF_SSC + t]; }

    // ---- stage x halo into LDS (bf16) ----
    {
        const float* xb = x + (size_t)b * NC * 65536;
        for (int i = t; i < NC * NPOS; i += 256) {
            int c = i / NPOS, r = i - c * NPOS;
            int yy = r / HALO, xx = r - yy * HALO;
            int gy = y0 - 1 + yy, gx = x0 - 1 + xx;
            float v = 0.f;
            if ((unsigned)gy < 256u && (unsigned)gx < 256u)
                v = xb[c * 65536 + gy * 256 + gx];
            xs[c][r] = __float2bfloat16(v);
        }
    }
    // stage A weights: w31 [c][o] then wav [c][o]
    for (int i = t; i < 4096; i += 256)
        wb[i] = (i < 2048) ? wsf[OFF_W31 + i] : wsf[OFF_WAV + i - 2048];
    __syncthreads();

    // ---- stage A: compute t1, t2 on the full halo (zero outside image) ----
    for (int pos = t; pos < NPOS; pos += 256) {
        int yy = pos / HALO, xx = pos - yy * HALO;
        int gy = y0 - 1 + yy, gx = x0 - 1 + xx;
        bool valid = ((unsigned)gy < 256u) && ((unsigned)gx < 256u);
        float a1[32], a2[32];
        #pragma unroll
        for (int o = 0; o < 32; o++) { a1[o] = 0.f; a2[o] = 0.f; }
        for (int c = 0; c < 64; c++) {
            float xv = __bfloat162float(xs[c][pos]);
            const float4* w1 = (const float4*)&wb[c * 32];
            const float4* w2 = (const float4*)&wb[2048 + c * 32];
            #pragma unroll
            for (int q = 0; q < 8; q++) {
                float4 u = w1[q], v = w2[q];
                a1[4*q+0] += xv * u.x; a1[4*q+1] += xv * u.y;
                a1[4*q+2] += xv * u.z; a1[4*q+3] += xv * u.w;
                a2[4*q+0] += xv * v.x; a2[4*q+1] += xv * v.y;
                a2[4*q+2] += xv * v.z; a2[4*q+3] += xv * v.w;
            }
        }
        #pragma unroll
        for (int o = 0; o < 32; o++) {
            t1s[o][pos] = __float2bfloat16(valid ? a1[o] + wsf[OFF_B31 + o] : 0.f);
            t2s[o][pos] = __float2bfloat16(valid ? a2[o] + wsf[OFF_BAV + o] : 0.f);
        }
    }

    const int py = t >> 4, px = t & 15;
    const int hp = (py + 1) * HALO + (px + 1);
    const int gy = y0 + py, gx = x0 + px;
    float* outb = out + (size_t)b * 64 * 65536 + gy * 256 + gx;

    // ---- stage B: main 3x3 + branch 1x1 (chunk weights, 8 in-ch at a time) ----
    float am[32], a1x[32];
    #pragma unroll
    for (int o = 0; o < 32; o++) { am[o] = 0.f; a1x[o] = 0.f; }
    for (int cc = 0; cc < 8; cc++) {
        __syncthreads();   // protect previous wb readers
        for (int i = t; i < 2560; i += 256)
            wb[i] = (i < 2304) ? wsf[OFF_WM + cc * 2304 + i]
                               : wsf[OFF_W11 + cc * 256 + (i - 2304)];
        __syncthreads();
        for (int c8 = 0; c8 < 8; c8++) {
            const int c = cc * 8 + c8;
            float xc = __bfloat162float(xs[c][hp]);
            const float4* wv = (const float4*)&wb[2304 + c8 * 32];
            #pragma unroll
            for (int q = 0; q < 8; q++) {
                float4 u = wv[q];
                a1x[4*q+0] += xc * u.x; a1x[4*q+1] += xc * u.y;
                a1x[4*q+2] += xc * u.z; a1x[4*q+3] += xc * u.w;
            }
            #pragma unroll
            for (int tap = 0; tap < 9; tap++) {
                int off = (tap / 3 - 1) * HALO + (tap % 3 - 1);
                float xv = __bfloat162float(xs[c][hp + off]);
                const float4* wm4 = (const float4*)&wb[(c8 * 9 + tap) * 32];
                #pragma unroll
                for (int q = 0; q < 8; q++) {
                    float4 u = wm4[q];
                    am[4*q+0] += xv * u.x; am[4*q+1] += xv * u.y;
                    am[4*q+2] += xv * u.z; am[4*q+3] += xv * u.w;
                }
            }
        }
    }
    #pragma unroll
    for (int o = 0; o < 32; o++) {
        int r = och[o];        // branch_main occupies concat channels [0,32)
        if (r >= 0) outb[(size_t)r * 65536] = (am[o] + wsf[OFF_BM + o]) * ssc[o];
        int r2 = och[32 + o];  // branch_1x1 occupies [32,64)
        if (r2 >= 0) outb[(size_t)r2 * 65536] = (a1x[o] + wsf[OFF_B11 + o]) * ssc[32 + o];
    }

    // ---- stage C: 3x3 conv on t1 (chunk weights, 16 in-ch at a time) ----
    float a3[32];
    #pragma unroll
    for (int o = 0; o < 32; o++) a3[o] = 0.f;
    for (int cc = 0; cc < 2; cc++) {
        __syncthreads();
        for (int i = t; i < 4608; i += 256) wb[i] = wsf[OFF_W32 + cc * 4608 + i];
        __syncthreads();
        for (int c16 = 0; c16 < 16; c16++) {
            const int c = cc * 16 + c16;
            #pragma unroll
            for (int tap = 0; tap < 9; tap++) {
                int off = (tap / 3 - 1) * HALO + (tap % 3 - 1);
                float tv = __bfloat162float(t1s[c][hp + off]);
                const float4* w4 = (const float4*)&wb[(c16 * 9 + tap) * 32];
                #pragma unroll
                for (int q = 0; q < 8; q++) {
                    float4 u = w4[q];
                    a3[4*q+0] += tv * u.x; a3[4*q+1] += tv * u.y;
                    a3[4*q+2] += tv * u.z; a3[4*q+3] += tv * u.w;
                }
            }
        }
    }
    #pragma unroll
    for (int o = 0; o < 32; o++) {
        int r = och[64 + o];   // branch_3x3 occupies [64,96)
        if (r >= 0) outb[(size_t)r * 65536] = (a3[o] + wsf[OFF_B32 + o]) * ssc[64 + o];
    }

    // ---- stage D: avgpool(3x3,/9) on t2 + bn_avg_2 ----
    #pragma unroll
    for (int o = 0; o < 32; o++) {
        float s = 0.f;
        #pragma unroll
        for (int tap = 0; tap < 9; tap++) {
            int off = (tap / 3 - 1) * HALO + (tap % 3 - 1);
            s += __bfloat162float(t2s[o][hp + off]);
        }
        float val = wsf[OFF_S2 + o] * (s * (1.f / 9.f)) + wsf[OFF_T2B + o];
        int r = och[96 + o];   // branch_avg occupies [96,128)
        if (r >= 0) outb[(size_t)r * 65536] = val * ssc[96 + o];
    }
}

// ---------------------------------------------------------------------------
extern "C" void kernel_launch(void* const* d_in, const int* in_sizes, int n_in,
                              void* d_out, int out_size, void* d_ws, size_t ws_size,
                              hipStream_t stream)
{
    const float* x        = (const float*)d_in[0];
    const float* w_main   = (const float*)d_in[1];
    const float* bn_main  = (const float*)d_in[2];
    const float* w_1x1    = (const float*)d_in[3];
    const float* bn_1x1   = (const float*)d_in[4];
    const float* w_3x3_1  = (const float*)d_in[5];
    const float* bn_3x3_1 = (const float*)d_in[6];
    const float* w_3x3_2  = (const float*)d_in[7];
    const float* bn_3x3_2 = (const float*)d_in[8];
    const float* w_avg    = (const float*)d_in[9];
    const float* bn_avg_1 = (const float*)d_in[10];
    const float* bn_avg_2 = (const float*)d_in[11];
    const float* c_score  = (const float*)d_in[12];

    int*   och = (int*)d_ws;
    float* wsf = (float*)d_ws + 128;

    prep_kernel<<<1, 256, 0, stream>>>(c_score, w_main, bn_main, w_1x1, bn_1x1,
        w_3x3_1, bn_3x3_1, w_3x3_2, bn_3x3_2, w_avg, bn_avg_1, bn_avg_2,
        och, wsf);

    fused_kernel<<<dim3(NW / TILE, NH / TILE, NB), 256, 0, stream>>>(
        x, wsf, och, (float*)d_out);
}

// Round 2
// 224.433 us; speedup vs baseline: 10.3560x; 10.3560x over previous
//
#include <hip/hip_runtime.h>
#include <hip/hip_bf16.h>

// ---------------------------------------------------------------------------
// Round 2: implicit-GEMM MFMA (32x32x16 bf16) fused 4-branch conv + top-k.
// Tile 32w x 16h, halo 34x18=612 pos. M=positions, N=out-channels, K=in-ch.
// avg branch folded into a per-tap-constant 3x3 conv (pool commutes w/ 1x1).
// ---------------------------------------------------------------------------

typedef __attribute__((ext_vector_type(8))) short bf16x8;
typedef __attribute__((ext_vector_type(16))) float f32x16;

#define MFMA32(a,b,c) __builtin_amdgcn_mfma_f32_32x32x16_bf16(a,b,c,0,0,0)

__device__ __forceinline__ unsigned short f2bf(float f) {
    union { __hip_bfloat16 h; unsigned short u; } cv;
    cv.h = __float2bfloat16(f);
    return cv.u;
}

__device__ __forceinline__ f32x16 zero16() {
    f32x16 z;
    #pragma unroll
    for (int i = 0; i < 16; i++) z[i] = 0.f;
    return z;
}

// ---------------------------------------------------------------------------
// prep: top-k ranks, folded biases (fp32), folded bf16 weights into ws.
// ws layout: och[128] int @0 | biases fp32 @512 (6x32) | bf16 weights @2048:
//   wA[32o][64c] @e0, wMain[9][32][64] @e2048, wAvg[32][64] @e20480,
//   w1x1[32][64] @e22528, wC[9][32][32] @e24576   (e = element index)
// ---------------------------------------------------------------------------
__global__ void prep_kernel(
    const float* __restrict__ c_score,
    const float* __restrict__ w_main, const float* __restrict__ bn_main,
    const float* __restrict__ w_1x1,  const float* __restrict__ bn_1x1,
    const float* __restrict__ w_3x3_1,const float* __restrict__ bn_3x3_1,
    const float* __restrict__ w_3x3_2,const float* __restrict__ bn_3x3_2,
    const float* __restrict__ w_avg,  const float* __restrict__ bn_avg_1,
    const float* __restrict__ bn_avg_2,
    int* __restrict__ och, float* __restrict__ biasb,
    __hip_bfloat16* __restrict__ wb)
{
    const int t = threadIdx.x;
    __shared__ float ssc[128];
    __shared__ float invM[32], inv11[32], inv31[32], inv32[32], invA1[32], s2s[32];

    if (t < 128) {
        float sj = c_score[t];
        int r = 0;
        for (int i = 0; i < 128; i++) {
            float si = c_score[i];
            r += (si > sj) || (si == sj && i < t);
        }
        och[t] = (r < 64) ? r : -1;
        ssc[t] = 1.f / (1.f + expf(-sj));
    }
    if (t < 32) {
        invM[t]  = bn_main[t]  * rsqrtf(bn_main[96+t]  + 1e-5f);
        inv11[t] = bn_1x1[t]   * rsqrtf(bn_1x1[96+t]   + 1e-5f);
        inv31[t] = bn_3x3_1[t] * rsqrtf(bn_3x3_1[96+t] + 1e-5f);
        inv32[t] = bn_3x3_2[t] * rsqrtf(bn_3x3_2[96+t] + 1e-5f);
        invA1[t] = bn_avg_1[t] * rsqrtf(bn_avg_1[96+t] + 1e-5f);
        s2s[t]   = bn_avg_2[t] * rsqrtf(bn_avg_2[96+t] + 1e-5f);
    }
    __syncthreads();

    for (int i = t; i < 2048; i += 256) {
        int o = i >> 6, c = i & 63;
        wb[i]         = __float2bfloat16(w_3x3_1[o*64+c] * inv31[o]);
        wb[20480 + i] = __float2bfloat16(w_avg[o*64+c] * invA1[o] * s2s[o] * (1.f/9.f) * ssc[96+o]);
        wb[22528 + i] = __float2bfloat16(w_1x1[o*64+c] * inv11[o] * ssc[32+o]);
    }
    for (int i = t; i < 18432; i += 256) {
        int tap = i >> 11, r2 = i & 2047, o = r2 >> 6, c = r2 & 63;
        wb[2048 + i] = __float2bfloat16(w_main[o*576 + c*9 + tap] * invM[o] * ssc[o]);
    }
    for (int i = t; i < 9216; i += 256) {
        int tap = i >> 10, r2 = i & 1023, o = r2 >> 5, c = r2 & 31;
        wb[24576 + i] = __float2bfloat16(w_3x3_2[o*288 + c*9 + tap] * inv32[o] * ssc[64+o]);
    }
    if (t < 32) {
        biasb[t]       = bn_3x3_1[32+t] - bn_3x3_1[64+t]*inv31[t];              // t1 bias (unscaled)
        biasb[32+t]    = (bn_main[32+t]  - bn_main[64+t]*invM[t])   * ssc[t];   // main
        biasb[64+t]    = (bn_1x1[32+t]   - bn_1x1[64+t]*inv11[t])   * ssc[32+t];// 1x1
        biasb[96+t]    = (bn_3x3_2[32+t] - bn_3x3_2[64+t]*inv32[t]) * ssc[64+t];// 3x3
        biasb[128+t]   = (bn_avg_2[32+t] - bn_avg_2[64+t]*s2s[t])   * ssc[96+t];// avg t2b
        float b1p = bn_avg_1[32+t] - bn_avg_1[64+t]*invA1[t];
        biasb[160+t]   = ssc[96+t] * s2s[t] * b1p * (1.f/9.f);                  // avg b1*s2/9
    }
}

// ---------------------------------------------------------------------------
__device__ __forceinline__ void store4(float* outb, const f32x16& acc,
    const int* __restrict__ och_g, const float* __restrict__ bias32,
    int cbase, int y, int x0, int i31, int g)
{
    int rank = och_g[cbase + i31];
    if (rank < 0) return;
    float bias = bias32[i31];
    float* po = outb + (size_t)rank * 65536 + y*256 + x0 + 4*g;
    #pragma unroll
    for (int q = 0; q < 4; q++) {
        float4 v;
        v.x = acc[4*q+0] + bias;
        v.y = acc[4*q+1] + bias;
        v.z = acc[4*q+2] + bias;
        v.w = acc[4*q+3] + bias;
        *(float4*)(po + 8*q) = v;
    }
}

__device__ __forceinline__ void store4avg(float* outb, const f32x16& acc,
    const int* __restrict__ och_g, const float* __restrict__ biasb,
    int y, int x0, int i31, int g)
{
    int rank = och_g[96 + i31];
    if (rank < 0) return;
    float t2b = biasb[128 + i31];
    float b19 = biasb[160 + i31];
    float cy = 3.f - (float)(y == 0) - (float)(y == 255);
    float* po = outb + (size_t)rank * 65536 + y*256 + x0 + 4*g;
    #pragma unroll
    for (int q = 0; q < 4; q++) {
        float4 v;
        #pragma unroll
        for (int u = 0; u < 4; u++) {
            int gx = x0 + 4*g + 8*q + u;
            float cx = 3.f - (float)(gx == 0) - (float)(gx == 255);
            ((float*)&v)[u] = acc[4*q+u] + t2b + b19 * (cy * cx);
        }
        *(float4*)(po + 8*q) = v;
    }
}

// ---------------------------------------------------------------------------
__global__ __launch_bounds__(512, 2) void fused_kernel(
    const float* __restrict__ x,
    const __hip_bfloat16* __restrict__ Wg,
    const int* __restrict__ och_g,
    const float* __restrict__ biasb,
    float* __restrict__ out)
{
    __shared__ __align__(16) unsigned char xs[640 * 128];   // [pos][64ch] bf16, swz ((pos&7)<<4)
    __shared__ __align__(16) unsigned char t1s[612 * 64];   // [pos][32ch] bf16, swz ((pos&3)<<4)

    const int t = threadIdx.x;
    const int lane = t & 63, wv = t >> 6;
    const int i31 = lane & 31, g = lane >> 5;
    const int x0 = blockIdx.x * 32, y0 = blockIdx.y * 16;
    const int b = blockIdx.z;

    // ---- stage x halo: transpose NCHW -> [pos][ch] bf16, XOR-swizzled ----
    const float* xb = x + (size_t)b * (64 * 65536);
    for (int j = t; j < 9792; j += 512) {            // 16 cquads * 612 pos
        int cq = j / 612, pos = j - cq * 612;
        int hy = pos / 34, hx = pos - hy * 34;
        int gy = y0 - 1 + hy, gx = x0 - 1 + hx;
        bool v = ((unsigned)gy < 256u) && ((unsigned)gx < 256u);
        const float* p = xb + (size_t)cq * 4 * 65536 + gy * 256 + gx;
        float f0 = v ? p[0]      : 0.f;
        float f1 = v ? p[65536]  : 0.f;
        float f2 = v ? p[131072] : 0.f;
        float f3 = v ? p[196608] : 0.f;
        unsigned int lo = (unsigned)f2bf(f0) | ((unsigned)f2bf(f1) << 16);
        unsigned int hi = (unsigned)f2bf(f2) | ((unsigned)f2bf(f3) << 16);
        unsigned long long q = ((unsigned long long)hi << 32) | lo;
        int addr = pos * 128 + ((cq * 8) ^ ((pos & 7) << 4));
        *(unsigned long long*)(xs + addr) = q;
    }
    __syncthreads();

    // ---- phase A: t1 = BN1(conv1x1(x, w_3x3_1)) over full halo ----
    {
        bf16x8 bA[4];
        #pragma unroll
        for (int s = 0; s < 4; s++)
            bA[s] = *(const bf16x8*)(Wg + (i31 * 64 + s * 16 + g * 8));
        float biasA = biasb[i31];
        for (int mt = wv; mt < 20; mt += 8) {
            int m0 = mt * 32;
            f32x16 acc = zero16();
            int posA = m0 + i31;
            int sw = (posA & 7) << 4;
            #pragma unroll
            for (int s = 0; s < 4; s++) {
                bf16x8 a = *(const bf16x8*)(xs + posA * 128 + ((s * 32 + g * 16) ^ sw));
                acc = MFMA32(a, bA[s], acc);
            }
            #pragma unroll
            for (int r = 0; r < 16; r++) {
                int pos = m0 + (r & 3) + 8 * (r >> 2) + 4 * g;
                if (pos < 612) {
                    int hy = pos / 34, hx = pos - hy * 34;
                    int gy = y0 - 1 + hy, gx = x0 - 1 + hx;
                    bool valid = ((unsigned)gy < 256u) && ((unsigned)gx < 256u);
                    float vv = valid ? (acc[r] + biasA) : 0.f;   // zero-pad t1 halo
                    *(unsigned short*)(t1s + pos * 64 + ((i31 * 2) ^ ((pos & 3) << 4))) = f2bf(vv);
                }
            }
        }
    }
    __syncthreads();

    float* outb = out + (size_t)b * (64 * 65536);

    // ---- phase B: main 3x3 + avg-as-3x3 + 1x1 (center tap) ----
    f32x16 aM[2], aG[2], aX[2];
    aM[0] = zero16(); aM[1] = zero16();
    aG[0] = zero16(); aG[1] = zero16();
    aX[0] = zero16(); aX[1] = zero16();
    {
        bf16x8 bg[4], bx[4];
        #pragma unroll
        for (int s = 0; s < 4; s++) {
            bg[s] = *(const bf16x8*)(Wg + 20480 + i31 * 64 + s * 16 + g * 8);
            bx[s] = *(const bf16x8*)(Wg + 22528 + i31 * 64 + s * 16 + g * 8);
        }
        for (int tap = 0; tap < 9; tap++) {
            int dy = tap / 3 - 1, dx = tap - (tap / 3) * 3 - 1;
            #pragma unroll
            for (int s = 0; s < 4; s++) {
                bf16x8 bm = *(const bf16x8*)(Wg + 2048 + (tap * 32 + i31) * 64 + s * 16 + g * 8);
                #pragma unroll
                for (int mt = 0; mt < 2; mt++) {
                    int tr = wv + mt * 8;
                    int pos = (tr + 1 + dy) * 34 + 1 + dx + i31;
                    bf16x8 a = *(const bf16x8*)(xs + pos * 128 + ((s * 32 + g * 16) ^ ((pos & 7) << 4)));
                    aM[mt] = MFMA32(a, bm, aM[mt]);
                    aG[mt] = MFMA32(a, bg[s], aG[mt]);
                    if (tap == 4) aX[mt] = MFMA32(a, bx[s], aX[mt]);
                }
            }
        }
    }
    #pragma unroll
    for (int mt = 0; mt < 2; mt++) {
        int y = y0 + wv + mt * 8;
        store4(outb, aM[mt], och_g, biasb + 32, 0,  y, x0, i31, g);   // main -> concat [0,32)
        store4(outb, aX[mt], och_g, biasb + 64, 32, y, x0, i31, g);   // 1x1  -> [32,64)
        store4avg(outb, aG[mt], och_g, biasb, y, x0, i31, g);         // avg  -> [96,128)
    }

    // ---- phase C: 3x3 conv on t1 ----
    f32x16 aC[2];
    aC[0] = zero16(); aC[1] = zero16();
    for (int tap = 0; tap < 9; tap++) {
        int dy = tap / 3 - 1, dx = tap - (tap / 3) * 3 - 1;
        #pragma unroll
        for (int s = 0; s < 2; s++) {
            bf16x8 bc = *(const bf16x8*)(Wg + 24576 + (tap * 32 + i31) * 32 + s * 16 + g * 8);
            #pragma unroll
            for (int mt = 0; mt < 2; mt++) {
                int tr = wv + mt * 8;
                int pos = (tr + 1 + dy) * 34 + 1 + dx + i31;
                bf16x8 a = *(const bf16x8*)(t1s + pos * 64 + ((s * 32 + g * 16) ^ ((pos & 3) << 4)));
                aC[mt] = MFMA32(a, bc, aC[mt]);
            }
        }
    }
    #pragma unroll
    for (int mt = 0; mt < 2; mt++) {
        int y = y0 + wv + mt * 8;
        store4(outb, aC[mt], och_g, biasb + 96, 64, y, x0, i31, g);   // 3x3 -> [64,96)
    }
}

// ---------------------------------------------------------------------------
extern "C" void kernel_launch(void* const* d_in, const int* in_sizes, int n_in,
                              void* d_out, int out_size, void* d_ws, size_t ws_size,
                              hipStream_t stream)
{
    const float* x        = (const float*)d_in[0];
    const float* w_main   = (const float*)d_in[1];
    const float* bn_main  = (const float*)d_in[2];
    const float* w_1x1    = (const float*)d_in[3];
    const float* bn_1x1   = (const float*)d_in[4];
    const float* w_3x3_1  = (const float*)d_in[5];
    const float* bn_3x3_1 = (const float*)d_in[6];
    const float* w_3x3_2  = (const float*)d_in[7];
    const float* bn_3x3_2 = (const float*)d_in[8];
    const float* w_avg    = (const float*)d_in[9];
    const float* bn_avg_1 = (const float*)d_in[10];
    const float* bn_avg_2 = (const float*)d_in[11];
    const float* c_score  = (const float*)d_in[12];

    int*   och   = (int*)d_ws;
    float* biasb = (float*)((char*)d_ws + 512);
    __hip_bfloat16* wb = (__hip_bfloat16*)((char*)d_ws + 2048);

    prep_kernel<<<1, 256, 0, stream>>>(c_score, w_main, bn_main, w_1x1, bn_1x1,
        w_3x3_1, bn_3x3_1, w_3x3_2, bn_3x3_2, w_avg, bn_avg_1, bn_avg_2,
        och, biasb, wb);

    fused_kernel<<<dim3(8, 16, 8), 512, 0, stream>>>(
        x, wb, och, biasb, (float*)d_out);
}

// Round 3
// 196.102 us; speedup vs baseline: 11.8522x; 1.1445x over previous
//
#include <hip/hip_runtime.h>
#include <hip/hip_bf16.h>

// ---------------------------------------------------------------------------
// Round 3: 32x8 tile, 40-wide aligned halo, 2 blocks/CU, vectorized staging.
// Implicit-GEMM MFMA (32x32x16 bf16), all 4 branches fused, top-k scatter.
// ---------------------------------------------------------------------------

typedef __attribute__((ext_vector_type(8))) short bf16x8;
typedef __attribute__((ext_vector_type(16))) float f32x16;
typedef __attribute__((ext_vector_type(4))) unsigned int u32x4;

#define MFMA32(a,b,c) __builtin_amdgcn_mfma_f32_32x32x16_bf16(a,b,c,0,0,0)

__device__ __forceinline__ unsigned short f2bf(float f) {
    union { __hip_bfloat16 h; unsigned short u; } cv;
    cv.h = __float2bfloat16(f);
    return cv.u;
}

__device__ __forceinline__ f32x16 zero16() {
    f32x16 z;
    #pragma unroll
    for (int i = 0; i < 16; i++) z[i] = 0.f;
    return z;
}

// xs: [400 pos][64ch] bf16, 128-B rows, slot-swizzle by (pos>>2)&7
__device__ __forceinline__ int xs_addr(int pos, int byteoff) {
    return pos * 128 + (byteoff ^ (((pos >> 2) & 7) << 4));
}
// t1s: [340 pos][32ch] bf16, 64-B rows, slot-swizzle by pos&3
__device__ __forceinline__ int t1_addr(int pos, int byteoff) {
    return pos * 64 + (byteoff ^ ((pos & 3) << 4));
}

// ---------------------------------------------------------------------------
// prep: identical to round 2 (verified).
// ws: och[128] int @0 | biases fp32 @512 | bf16 weights @2048:
//   wA[32o][64c] @e0, wMain[9][32][64] @e2048, wAvg[32][64] @e20480,
//   w1x1[32][64] @e22528, wC[9][32][32] @e24576
// ---------------------------------------------------------------------------
__global__ void prep_kernel(
    const float* __restrict__ c_score,
    const float* __restrict__ w_main, const float* __restrict__ bn_main,
    const float* __restrict__ w_1x1,  const float* __restrict__ bn_1x1,
    const float* __restrict__ w_3x3_1,const float* __restrict__ bn_3x3_1,
    const float* __restrict__ w_3x3_2,const float* __restrict__ bn_3x3_2,
    const float* __restrict__ w_avg,  const float* __restrict__ bn_avg_1,
    const float* __restrict__ bn_avg_2,
    int* __restrict__ och, float* __restrict__ biasb,
    __hip_bfloat16* __restrict__ wb)
{
    const int t = threadIdx.x;
    __shared__ float ssc[128];
    __shared__ float invM[32], inv11[32], inv31[32], inv32[32], invA1[32], s2s[32];

    if (t < 128) {
        float sj = c_score[t];
        int r = 0;
        for (int i = 0; i < 128; i++) {
            float si = c_score[i];
            r += (si > sj) || (si == sj && i < t);
        }
        och[t] = (r < 64) ? r : -1;
        ssc[t] = 1.f / (1.f + expf(-sj));
    }
    if (t < 32) {
        invM[t]  = bn_main[t]  * rsqrtf(bn_main[96+t]  + 1e-5f);
        inv11[t] = bn_1x1[t]   * rsqrtf(bn_1x1[96+t]   + 1e-5f);
        inv31[t] = bn_3x3_1[t] * rsqrtf(bn_3x3_1[96+t] + 1e-5f);
        inv32[t] = bn_3x3_2[t] * rsqrtf(bn_3x3_2[96+t] + 1e-5f);
        invA1[t] = bn_avg_1[t] * rsqrtf(bn_avg_1[96+t] + 1e-5f);
        s2s[t]   = bn_avg_2[t] * rsqrtf(bn_avg_2[96+t] + 1e-5f);
    }
    __syncthreads();

    for (int i = t; i < 2048; i += 256) {
        int o = i >> 6, c = i & 63;
        wb[i]         = __float2bfloat16(w_3x3_1[o*64+c] * inv31[o]);
        wb[20480 + i] = __float2bfloat16(w_avg[o*64+c] * invA1[o] * s2s[o] * (1.f/9.f) * ssc[96+o]);
        wb[22528 + i] = __float2bfloat16(w_1x1[o*64+c] * inv11[o] * ssc[32+o]);
    }
    for (int i = t; i < 18432; i += 256) {
        int tap = i >> 11, r2 = i & 2047, o = r2 >> 6, c = r2 & 63;
        wb[2048 + i] = __float2bfloat16(w_main[o*576 + c*9 + tap] * invM[o] * ssc[o]);
    }
    for (int i = t; i < 9216; i += 256) {
        int tap = i >> 10, r2 = i & 1023, o = r2 >> 5, c = r2 & 31;
        wb[24576 + i] = __float2bfloat16(w_3x3_2[o*288 + c*9 + tap] * inv32[o] * ssc[64+o]);
    }
    if (t < 32) {
        biasb[t]       = bn_3x3_1[32+t] - bn_3x3_1[64+t]*inv31[t];
        biasb[32+t]    = (bn_main[32+t]  - bn_main[64+t]*invM[t])   * ssc[t];
        biasb[64+t]    = (bn_1x1[32+t]   - bn_1x1[64+t]*inv11[t])   * ssc[32+t];
        biasb[96+t]    = (bn_3x3_2[32+t] - bn_3x3_2[64+t]*inv32[t]) * ssc[64+t];
        biasb[128+t]   = (bn_avg_2[32+t] - bn_avg_2[64+t]*s2s[t])   * ssc[96+t];
        float b1p = bn_avg_1[32+t] - bn_avg_1[64+t]*invA1[t];
        biasb[160+t]   = ssc[96+t] * s2s[t] * b1p * (1.f/9.f);
    }
}

// ---------------------------------------------------------------------------
__device__ __forceinline__ void store4(float* outb, const f32x16& acc,
    const int* __restrict__ och_g, const float* __restrict__ bias32,
    int cbase, int y, int x0, int i31, int g)
{
    int rank = och_g[cbase + i31];
    if (rank < 0) return;
    float bias = bias32[i31];
    float* po = outb + (size_t)rank * 65536 + y*256 + x0 + 4*g;
    #pragma unroll
    for (int q = 0; q < 4; q++) {
        float4 v;
        v.x = acc[4*q+0] + bias;
        v.y = acc[4*q+1] + bias;
        v.z = acc[4*q+2] + bias;
        v.w = acc[4*q+3] + bias;
        *(float4*)(po + 8*q) = v;
    }
}

__device__ __forceinline__ void store4avg(float* outb, const f32x16& acc,
    const int* __restrict__ och_g, const float* __restrict__ biasb,
    int y, int x0, int i31, int g)
{
    int rank = och_g[96 + i31];
    if (rank < 0) return;
    float t2b = biasb[128 + i31];
    float b19 = biasb[160 + i31];
    float cy = 3.f - (float)(y == 0) - (float)(y == 255);
    float* po = outb + (size_t)rank * 65536 + y*256 + x0 + 4*g;
    #pragma unroll
    for (int q = 0; q < 4; q++) {
        float4 v;
        #pragma unroll
        for (int u = 0; u < 4; u++) {
            int gx = x0 + 4*g + 8*q + u;
            float cx = 3.f - (float)(gx == 0) - (float)(gx == 255);
            ((float*)&v)[u] = acc[4*q+u] + t2b + b19 * (cy * cx);
        }
        *(float4*)(po + 8*q) = v;
    }
}

// ---------------------------------------------------------------------------
__global__ __launch_bounds__(512, 4) void fused_kernel(
    const float* __restrict__ x,
    const __hip_bfloat16* __restrict__ Wg,
    const int* __restrict__ och_g,
    const float* __restrict__ biasb,
    float* __restrict__ out)
{
    __shared__ __align__(16) unsigned char xs[400 * 128];   // 51200 B
    __shared__ __align__(16) unsigned char t1s[340 * 64];   // 21760 B

    const int t = threadIdx.x;
    const int lane = t & 63, wv = t >> 6;
    const int i31 = lane & 31, g = lane >> 5;
    const int x0 = blockIdx.x * 32, y0 = blockIdx.y * 8;
    const int b = blockIdx.z;

    // ---- stage x halo: [row 0..9][col 0..39] <- image [y0-1..y0+8][x0-4..x0+35]
    // thread j: channel-octet co, row, x-quad xq. 16B-aligned float4 loads,
    // ds_write_b128 of 8 packed bf16 channels per position.
    const float* xb = x + (size_t)b * (64 * 65536);
    for (int j = t; j < 800; j += 512) {
        int co = j / 100;
        int rem = j - co * 100;
        int row = rem / 10, xq = rem - row * 10;
        int gy = y0 - 1 + row;
        int gx0 = x0 - 4 + 4 * xq;
        bool ok = ((unsigned)gy < 256u) && ((unsigned)gx0 <= 252u);
        const float* p = xb + (size_t)(co * 8) * 65536 + (size_t)gy * 256 + gx0;
        float4 f0 = {0,0,0,0}, f1 = {0,0,0,0}, f2 = {0,0,0,0}, f3 = {0,0,0,0};
        float4 f4 = {0,0,0,0}, f5 = {0,0,0,0}, f6 = {0,0,0,0}, f7 = {0,0,0,0};
        if (ok) {
            f0 = *(const float4*)(p);
            f1 = *(const float4*)(p + 65536);
            f2 = *(const float4*)(p + 131072);
            f3 = *(const float4*)(p + 196608);
            f4 = *(const float4*)(p + 262144);
            f5 = *(const float4*)(p + 327680);
            f6 = *(const float4*)(p + 393216);
            f7 = *(const float4*)(p + 458752);
        }
        const float* fv[8] = {(const float*)&f0, (const float*)&f1, (const float*)&f2,
                              (const float*)&f3, (const float*)&f4, (const float*)&f5,
                              (const float*)&f6, (const float*)&f7};
        #pragma unroll
        for (int u = 0; u < 4; u++) {
            int pos = row * 40 + 4 * xq + u;
            u32x4 w;
            w[0] = (unsigned)f2bf(fv[0][u]) | ((unsigned)f2bf(fv[1][u]) << 16);
            w[1] = (unsigned)f2bf(fv[2][u]) | ((unsigned)f2bf(fv[3][u]) << 16);
            w[2] = (unsigned)f2bf(fv[4][u]) | ((unsigned)f2bf(fv[5][u]) << 16);
            w[3] = (unsigned)f2bf(fv[6][u]) | ((unsigned)f2bf(fv[7][u]) << 16);
            *(u32x4*)(xs + xs_addr(pos, co * 16)) = w;
        }
    }
    __syncthreads();

    // ---- phase A: t1 = BN1(conv1x1(x, w_3x3_1)) over 34x10 t1-halo ----
    {
        bf16x8 bA[4];
        #pragma unroll
        for (int s = 0; s < 4; s++)
            bA[s] = *(const bf16x8*)(Wg + (i31 * 64 + s * 16 + g * 8));
        float biasA = biasb[i31];
        for (int mt = wv; mt < 11; mt += 8) {
            int m0 = mt * 32;
            f32x16 acc = zero16();
            int qr = m0 + i31; if (qr > 339) qr = 339;
            int hy = qr / 34, hx = qr - hy * 34;
            int pos = hy * 40 + hx + 3;           // t1 col q maps to xs col q+3
            #pragma unroll
            for (int s = 0; s < 4; s++) {
                bf16x8 a = *(const bf16x8*)(xs + xs_addr(pos, s * 32 + g * 16));
                acc = MFMA32(a, bA[s], acc);
            }
            #pragma unroll
            for (int r = 0; r < 16; r++) {
                int q = m0 + (r & 3) + 8 * (r >> 2) + 4 * g;
                if (q < 340) {
                    int hy2 = q / 34, hx2 = q - hy2 * 34;
                    int gy = y0 - 1 + hy2, gx = x0 - 1 + hx2;
                    bool valid = ((unsigned)gy < 256u) && ((unsigned)gx < 256u);
                    float vv = valid ? (acc[r] + biasA) : 0.f;
                    *(unsigned short*)(t1s + t1_addr(q, i31 * 2)) = f2bf(vv);
                }
            }
        }
    }
    __syncthreads();

    float* outb = out + (size_t)b * (64 * 65536);
    const int y = y0 + wv;                 // each wave owns one output row

    // ---- phase B: main 3x3 + avg-as-3x3 + 1x1 (center tap) ----
    f32x16 aM = zero16(), aG = zero16(), aX = zero16();
    {
        bf16x8 bg[4], bx[4];
        #pragma unroll
        for (int s = 0; s < 4; s++) {
            bg[s] = *(const bf16x8*)(Wg + 20480 + i31 * 64 + s * 16 + g * 8);
            bx[s] = *(const bf16x8*)(Wg + 22528 + i31 * 64 + s * 16 + g * 8);
        }
        for (int tap = 0; tap < 9; tap++) {
            int dy = tap / 3 - 1, dx = tap - (tap / 3) * 3 - 1;
            int pos = (wv + 1 + dy) * 40 + 4 + dx + i31;
            #pragma unroll
            for (int s = 0; s < 4; s++) {
                bf16x8 bm = *(const bf16x8*)(Wg + 2048 + (tap * 32 + i31) * 64 + s * 16 + g * 8);
                bf16x8 a = *(const bf16x8*)(xs + xs_addr(pos, s * 32 + g * 16));
                aM = MFMA32(a, bm, aM);
                aG = MFMA32(a, bg[s], aG);
                if (tap == 4) aX = MFMA32(a, bx[s], aX);
            }
        }
    }
    store4(outb, aM, och_g, biasb + 32, 0,  y, x0, i31, g);   // main -> [0,32)
    store4(outb, aX, och_g, biasb + 64, 32, y, x0, i31, g);   // 1x1  -> [32,64)
    store4avg(outb, aG, och_g, biasb, y, x0, i31, g);         // avg  -> [96,128)

    // ---- phase C: 3x3 conv on t1 ----
    f32x16 aC = zero16();
    for (int tap = 0; tap < 9; tap++) {
        int dy = tap / 3 - 1, dx = tap - (tap / 3) * 3 - 1;
        int q = (wv + 1 + dy) * 34 + 1 + dx + i31;
        #pragma unroll
        for (int s = 0; s < 2; s++) {
            bf16x8 bc = *(const bf16x8*)(Wg + 24576 + (tap * 32 + i31) * 32 + s * 16 + g * 8);
            bf16x8 a = *(const bf16x8*)(t1s + t1_addr(q, s * 32 + g * 16));
            aC = MFMA32(a, bc, aC);
        }
    }
    store4(outb, aC, och_g, biasb + 96, 64, y, x0, i31, g);   // 3x3 -> [64,96)
}

// ---------------------------------------------------------------------------
extern "C" void kernel_launch(void* const* d_in, const int* in_sizes, int n_in,
                              void* d_out, int out_size, void* d_ws, size_t ws_size,
                              hipStream_t stream)
{
    const float* x        = (const float*)d_in[0];
    const float* w_main   = (const float*)d_in[1];
    const float* bn_main  = (const float*)d_in[2];
    const float* w_1x1    = (const float*)d_in[3];
    const float* bn_1x1   = (const float*)d_in[4];
    const float* w_3x3_1  = (const float*)d_in[5];
    const float* bn_3x3_1 = (const float*)d_in[6];
    const float* w_3x3_2  = (const float*)d_in[7];
    const float* bn_3x3_2 = (const float*)d_in[8];
    const float* w_avg    = (const float*)d_in[9];
    const float* bn_avg_1 = (const float*)d_in[10];
    const float* bn_avg_2 = (const float*)d_in[11];
    const float* c_score  = (const float*)d_in[12];

    int*   och   = (int*)d_ws;
    float* biasb = (float*)((char*)d_ws + 512);
    __hip_bfloat16* wb = (__hip_bfloat16*)((char*)d_ws + 2048);

    prep_kernel<<<1, 256, 0, stream>>>(c_score, w_main, bn_main, w_1x1, bn_1x1,
        w_3x3_1, bn_3x3_1, w_3x3_2, bn_3x3_2, w_avg, bn_avg_1, bn_avg_2,
        och, biasb, wb);

    fused_kernel<<<dim3(8, 32, 8), 512, 0, stream>>>(
        x, wb, och, biasb, (float*)d_out);
}